// Round 1
// baseline (49.199 us; speedup 1.0000x reference)
//
#include <hip/hip_runtime.h>

constexpr int IMG_H = 2048;
constexpr int IMG_W = 2048;

__device__ __forceinline__ void sort2(float& a, float& b) {
    float mn = fminf(a, b);
    float mx = fmaxf(a, b);
    a = mn;
    b = mx;
}

// Place min of a[0..S-1] at a[0] and max at a[S-1]; multiset preserved.
template <int S>
__device__ __forceinline__ void minmax_sweep(float* a) {
    constexpr int Hh = S / 2;
#pragma unroll
    for (int i = 0; i < Hh; ++i) sort2(a[i], a[S - 1 - i]);
    constexpr int M = (S - 1) / 2;
#pragma unroll
    for (int i = 1; i <= M; ++i) sort2(a[0], a[i]);
#pragma unroll
    for (int i = M; i <= S - 2; ++i) sort2(a[i], a[S - 1]);
}

__device__ __forceinline__ int reflect_idx(int i, int n) {
    i = (i < 0) ? -i : i;
    i = (i >= n) ? (2 * n - 2 - i) : i;
    return i;
}

__global__ __launch_bounds__(256) void median5x5_kernel(const float* __restrict__ img,
                                                        float* __restrict__ out) {
    const int x = blockIdx.x * blockDim.x + threadIdx.x;
    const int y = blockIdx.y * blockDim.y + threadIdx.y;
    if (x >= IMG_W || y >= IMG_H) return;

    int cols[5];
    int rows[5];
#pragma unroll
    for (int d = 0; d < 5; ++d) {
        cols[d] = reflect_idx(x + d - 2, IMG_W);
        rows[d] = reflect_idx(y + d - 2, IMG_H) * IMG_W;
    }

    float v[25];
#pragma unroll
    for (int i = 0; i < 5; ++i)
#pragma unroll
        for (int j = 0; j < 5; ++j) v[i * 5 + j] = img[rows[i] + cols[j]];

    // Forgetful selection: working set of 14, discard provable-non-median
    // min & max each sweep, refill one slot with the next window element.
    float w[14];
#pragma unroll
    for (int i = 0; i < 14; ++i) w[i] = v[i];

    minmax_sweep<14>(w); w[0] = v[14];
    minmax_sweep<13>(w); w[0] = v[15];
    minmax_sweep<12>(w); w[0] = v[16];
    minmax_sweep<11>(w); w[0] = v[17];
    minmax_sweep<10>(w); w[0] = v[18];
    minmax_sweep<9>(w);  w[0] = v[19];
    minmax_sweep<8>(w);  w[0] = v[20];
    minmax_sweep<7>(w);  w[0] = v[21];
    minmax_sweep<6>(w);  w[0] = v[22];
    minmax_sweep<5>(w);  w[0] = v[23];
    minmax_sweep<4>(w);  w[0] = v[24];

    // Survivors w[0..2] hold ranks 12..14 of 25; their median is rank 13.
    const float mx01 = fmaxf(w[0], w[1]);
    const float mn01 = fminf(w[0], w[1]);
    const float med = fmaxf(mn01, fminf(mx01, w[2]));

    out[y * IMG_W + x] = med;
}

extern "C" void kernel_launch(void* const* d_in, const int* in_sizes, int n_in,
                              void* d_out, int out_size, void* d_ws, size_t ws_size,
                              hipStream_t stream) {
    const float* img = (const float*)d_in[0];
    float* out = (float*)d_out;
    dim3 block(64, 4);
    dim3 grid(IMG_W / 64, IMG_H / 4);
    median5x5_kernel<<<grid, block, 0, stream>>>(img, out);
}

// Round 2
// 33.265 us; speedup vs baseline: 1.4790x; 1.4790x over previous
//
#include <hip/hip_runtime.h>

constexpr int IMG_H = 2048;
constexpr int IMG_W = 2048;

// compare-exchange: a=min, b=max
#define CE(a, b) { float _mn = fminf(a, b); b = fmaxf(a, b); a = _mn; }

// minmax sweep over S named values: min -> first, max -> last, multiset preserved
__device__ __forceinline__ void sw14(float& a0, float& a1, float& a2, float& a3, float& a4,
                                     float& a5, float& a6, float& a7, float& a8, float& a9,
                                     float& a10, float& a11, float& a12, float& a13) {
    CE(a0, a13) CE(a1, a12) CE(a2, a11) CE(a3, a10) CE(a4, a9) CE(a5, a8) CE(a6, a7)
    CE(a0, a1) CE(a0, a2) CE(a0, a3) CE(a0, a4) CE(a0, a5) CE(a0, a6)
    CE(a6, a13) CE(a7, a13) CE(a8, a13) CE(a9, a13) CE(a10, a13) CE(a11, a13) CE(a12, a13)
}
__device__ __forceinline__ void sw13(float& a0, float& a1, float& a2, float& a3, float& a4,
                                     float& a5, float& a6, float& a7, float& a8, float& a9,
                                     float& a10, float& a11, float& a12) {
    CE(a0, a12) CE(a1, a11) CE(a2, a10) CE(a3, a9) CE(a4, a8) CE(a5, a7)
    CE(a0, a1) CE(a0, a2) CE(a0, a3) CE(a0, a4) CE(a0, a5) CE(a0, a6)
    CE(a6, a12) CE(a7, a12) CE(a8, a12) CE(a9, a12) CE(a10, a12) CE(a11, a12)
}
__device__ __forceinline__ void sw12(float& a0, float& a1, float& a2, float& a3, float& a4,
                                     float& a5, float& a6, float& a7, float& a8, float& a9,
                                     float& a10, float& a11) {
    CE(a0, a11) CE(a1, a10) CE(a2, a9) CE(a3, a8) CE(a4, a7) CE(a5, a6)
    CE(a0, a1) CE(a0, a2) CE(a0, a3) CE(a0, a4) CE(a0, a5)
    CE(a5, a11) CE(a6, a11) CE(a7, a11) CE(a8, a11) CE(a9, a11) CE(a10, a11)
}
__device__ __forceinline__ void sw11(float& a0, float& a1, float& a2, float& a3, float& a4,
                                     float& a5, float& a6, float& a7, float& a8, float& a9,
                                     float& a10) {
    CE(a0, a10) CE(a1, a9) CE(a2, a8) CE(a3, a7) CE(a4, a6)
    CE(a0, a1) CE(a0, a2) CE(a0, a3) CE(a0, a4) CE(a0, a5)
    CE(a5, a10) CE(a6, a10) CE(a7, a10) CE(a8, a10) CE(a9, a10)
}
__device__ __forceinline__ void sw10(float& a0, float& a1, float& a2, float& a3, float& a4,
                                     float& a5, float& a6, float& a7, float& a8, float& a9) {
    CE(a0, a9) CE(a1, a8) CE(a2, a7) CE(a3, a6) CE(a4, a5)
    CE(a0, a1) CE(a0, a2) CE(a0, a3) CE(a0, a4)
    CE(a4, a9) CE(a5, a9) CE(a6, a9) CE(a7, a9) CE(a8, a9)
}
__device__ __forceinline__ void sw9(float& a0, float& a1, float& a2, float& a3, float& a4,
                                    float& a5, float& a6, float& a7, float& a8) {
    CE(a0, a8) CE(a1, a7) CE(a2, a6) CE(a3, a5)
    CE(a0, a1) CE(a0, a2) CE(a0, a3) CE(a0, a4)
    CE(a4, a8) CE(a5, a8) CE(a6, a8) CE(a7, a8)
}
__device__ __forceinline__ void sw8(float& a0, float& a1, float& a2, float& a3, float& a4,
                                    float& a5, float& a6, float& a7) {
    CE(a0, a7) CE(a1, a6) CE(a2, a5) CE(a3, a4)
    CE(a0, a1) CE(a0, a2) CE(a0, a3)
    CE(a3, a7) CE(a4, a7) CE(a5, a7) CE(a6, a7)
}
__device__ __forceinline__ void sw7(float& a0, float& a1, float& a2, float& a3, float& a4,
                                    float& a5, float& a6) {
    CE(a0, a6) CE(a1, a5) CE(a2, a4)
    CE(a0, a1) CE(a0, a2) CE(a0, a3)
    CE(a3, a6) CE(a4, a6) CE(a5, a6)
}
__device__ __forceinline__ void sw6(float& a0, float& a1, float& a2, float& a3, float& a4,
                                    float& a5) {
    CE(a0, a5) CE(a1, a4) CE(a2, a3)
    CE(a0, a1) CE(a0, a2)
    CE(a2, a5) CE(a3, a5) CE(a4, a5)
}

// tail for one pixel: 8 shared survivors + 5 private column values -> median of 25
__device__ __forceinline__ float tail5(float l1, float l2, float l3, float l4, float l5,
                                       float l6, float l7, float l8,
                                       float p0, float p1, float p2, float p3, float p4) {
    float l0 = p0;
    sw9(l0, l1, l2, l3, l4, l5, l6, l7, l8);   // discard l0,l8
    l0 = p1;
    sw8(l0, l1, l2, l3, l4, l5, l6, l7);       // discard l0,l7
    l0 = p2;
    sw7(l0, l1, l2, l3, l4, l5, l6);           // discard l0,l6
    l0 = p3;
    sw6(l0, l1, l2, l3, l4, l5);               // discard l0,l5
    l0 = p4;
    // 5 survivors hold ranks 11..15 of 25 -> median of 5 = rank 13
    CE(l0, l1) CE(l3, l4) CE(l0, l3) CE(l1, l4)  // l0=min, l4=max of {l0,l1,l3,l4} -> excluded
    return __builtin_amdgcn_fmed3f(l1, l2, l3);
}

__global__ __launch_bounds__(256) void median5x5_kernel(const float* __restrict__ img,
                                                        float* __restrict__ out) {
    const int t = blockIdx.x * blockDim.x + threadIdx.x;  // pixel-pair index
    const int y = blockIdx.y * blockDim.y + threadIdx.y;
    const int xL = 2 * t;  // left pixel; right = xL+1

    // reflected row bases
    int r0 = y - 2, r1 = y - 1, r2 = y, r3 = y + 1, r4 = y + 2;
    r0 = (r0 < 0) ? -r0 : r0;
    r1 = (r1 < 0) ? -r1 : r1;
    r3 = (r3 >= IMG_H) ? 2 * IMG_H - 2 - r3 : r3;
    r4 = (r4 >= IMG_H) ? 2 * IMG_H - 2 - r4 : r4;
    const int ry0 = r0 * IMG_W, ry1 = r1 * IMG_W, ry2 = r2 * IMG_W,
              ry3 = r3 * IMG_W, ry4 = r4 * IMG_W;

    // reflected column indices xL-2 .. xL+3
    int c0 = xL - 2, c1 = xL - 1, c2 = xL, c3 = xL + 1, c4 = xL + 2, c5 = xL + 3;
    c0 = (c0 < 0) ? -c0 : c0;
    c1 = (c1 < 0) ? -c1 : c1;
    c4 = (c4 >= IMG_W) ? 2 * IMG_W - 2 - c4 : c4;
    c5 = (c5 >= IMG_W) ? 2 * IMG_W - 2 - c5 : c5;

    // shared 20 = cols c1..c4 x 5 rows. First 14 into working set, 6 deferred.
    float w0 = img[ry0 + c1], w1 = img[ry0 + c2], w2 = img[ry0 + c3], w3 = img[ry0 + c4];
    float w4 = img[ry1 + c1], w5 = img[ry1 + c2], w6 = img[ry1 + c3], w7 = img[ry1 + c4];
    float w8 = img[ry2 + c1], w9 = img[ry2 + c2], w10 = img[ry2 + c3], w11 = img[ry2 + c4];
    float w12 = img[ry3 + c1], w13 = img[ry3 + c2];
    float e14 = img[ry3 + c3], e15 = img[ry3 + c4];
    float e16 = img[ry4 + c1], e17 = img[ry4 + c2], e18 = img[ry4 + c3], e19 = img[ry4 + c4];
    // private columns
    float p0 = img[ry0 + c0], p1 = img[ry1 + c0], p2 = img[ry2 + c0], p3 = img[ry3 + c0],
          p4 = img[ry4 + c0];
    float q0 = img[ry0 + c5], q1 = img[ry1 + c5], q2 = img[ry2 + c5], q3 = img[ry3 + c5],
          q4 = img[ry4 + c5];

    // shared forgetful phase: sweeps 14..9 over the 20 shared elements.
    // Each discard is safe: (s-1) in-set + prior opposite-side discards = 13.
    sw14(w0, w1, w2, w3, w4, w5, w6, w7, w8, w9, w10, w11, w12, w13);
    w0 = e14;
    sw13(w0, w1, w2, w3, w4, w5, w6, w7, w8, w9, w10, w11, w12);
    w0 = e15;
    sw12(w0, w1, w2, w3, w4, w5, w6, w7, w8, w9, w10, w11);
    w0 = e16;
    sw11(w0, w1, w2, w3, w4, w5, w6, w7, w8, w9, w10);
    w0 = e17;
    sw10(w0, w1, w2, w3, w4, w5, w6, w7, w8, w9);
    w0 = e18;
    sw9(w0, w1, w2, w3, w4, w5, w6, w7, w8);
    w0 = e19;
    // survivors {w0..w7} = middle 8 (ranks 7..14) of the shared 20

    const float medL = tail5(w0, w1, w2, w3, w4, w5, w6, w7, p0, p1, p2, p3, p4);
    const float medR = tail5(w0, w1, w2, w3, w4, w5, w6, w7, q0, q1, q2, q3, q4);

    float2 res = make_float2(medL, medR);
    *reinterpret_cast<float2*>(out + ry2 + xL) = res;
}

extern "C" void kernel_launch(void* const* d_in, const int* in_sizes, int n_in,
                              void* d_out, int out_size, void* d_ws, size_t ws_size,
                              hipStream_t stream) {
    const float* img = (const float*)d_in[0];
    float* out = (float*)d_out;
    dim3 block(64, 4);
    dim3 grid((IMG_W / 2) / 64, IMG_H / 4);
    median5x5_kernel<<<grid, block, 0, stream>>>(img, out);
}